// Round 5
// baseline (710.340 us; speedup 1.0000x reference)
//
#include <hip/hip_runtime.h>

// CTC forward loss, linear-space (scaled) forward algorithm, fp64 alpha.
// B=256, T=1024, C=256 (blank=255), L=128, S=2L+1=257.
// One 64-lane wave per batch element; lane l holds states 4l+1..4l+4 (fp64)
// plus replicated state 0. Neighbors via DPP WAVE_SHR1 (no barriers, waves
// fully independent -> no __syncthreads anywhere).
//
// Round-4 post-mortem: 252 us = ~600 cy/step = one memory round-trip per
// step; VALUBusy 4%. The 8-deep rbuf pipeline never overlapped across
// iterations (compiler-conservative waitcnt on the loop-carried load regs).
// Fix: hide the per-wave serialization with TLP -- 8 waves (8 batch rows)
// per block, 32 blocks. Per-SIMD: 2 waves x ~100cy VALU / 600cy = 33%;
// DS pipe ~53%; per-CU mem ~14 B/cy. Nothing saturates -> ~8x throughput.
// LDS ring shrunk 8->4 slots/wave (rows live in LDS only t+2..t+3) so
// 8 waves x 4 KB = 32 KB/block; VGPR rbuf ring stays 8-deep.

#define T_DIM 1024
#define C_DIM 256
#define L_DIM 128
#define EPSF  1e-7f
#define LN2D  0.69314718055994530942
#define DG    8   // gload -> ds_write pipeline depth (VGPR rbuf ring, &7)
#define DL    3   // ds_write happens DL steps ahead of compute
#define DS    2   // ds_read  happens DS steps ahead of compute
#define NSL   4   // LDS ring slots per wave (1 KB each, &3)
#define WPB   8   // waves (batch elements) per block

// shuffle-up-by-1 across the 64-lane wave (both halves); lane 0 gets `old`.
__device__ __forceinline__ double dpp_shr1_f64(double old, double v) {
    int rlo = __builtin_amdgcn_update_dpp(__double2loint(old), __double2loint(v),
                                          0x138 /*WAVE_SHR1*/, 0xF, 0xF, false);
    int rhi = __builtin_amdgcn_update_dpp(__double2hiint(old), __double2hiint(v),
                                          0x138 /*WAVE_SHR1*/, 0xF, 0xF, false);
    return __hiloint2double(rhi, rlo);
}

// wave-wide int max (inputs >= 0), result broadcast via readlane(63).
__device__ __forceinline__ int wave_imax_all(int v) {
#define STAGE(CTRL) { int t_ = __builtin_amdgcn_update_dpp(v, v, CTRL, 0xF, 0xF, false); \
                      v = v > t_ ? v : t_; }
    STAGE(0x111)  // row_shr:1
    STAGE(0x112)  // row_shr:2
    STAGE(0x114)  // row_shr:4
    STAGE(0x118)  // row_shr:8
    STAGE(0x142)  // row_bcast:15
    STAGE(0x143)  // row_bcast:31
#undef STAGE
    return __builtin_amdgcn_readlane(v, 63);
}

__device__ __forceinline__ void ctc_step(double p0, double p1, double pB,
                                         double k1, double k3, double& a0,
                                         double& r1, double& r2, double& r3, double& r4) {
    // neighbors from previous lane: A[4l] = prev.r4, A[4l-1] = prev.r3
    double sA4 = dpp_shr1_f64(a0,  r4);   // lane0 <- state 0 (a0)
    double sA3 = dpp_shr1_f64(0.0, r3);   // lane0 <- 0 (state -1)
    double n1 = p0 * fma(k1, sA3, r1 + sA4);  // odd state 4l+1 (label 2l)
    double n2 = pB * (r2 + r1);               // blank state 4l+2
    double n3 = p1 * fma(k3, r1, r3 + r2);    // odd state 4l+3 (label 2l+1)
    double n4 = pB * (r4 + r3);               // blank state 4l+4
    a0 *= pB;                                 // state 0: blank self-loop only
    r1 = n1; r2 = n2; r3 = n3; r4 = n4;
}

__global__ __launch_bounds__(WPB * 64, 1)
void ctc_fwd(const int* __restrict__ labels, const float* __restrict__ ypred,
             float* __restrict__ out) {
    const int wave = threadIdx.x >> 6;         // 0..WPB-1
    const int l    = threadIdx.x & 63;         // lane 0..63
    const int b    = blockIdx.x * WPB + wave;  // batch element
    const float* Yb = ypred + (size_t)b * (T_DIM * C_DIM);

    __shared__ float smem_all[WPB * NSL * C_DIM];  // 32 KB: 4-slot ring/wave
    float* smem = smem_all + wave * (NSL * C_DIM);

    // labels 2l, 2l+1 (L=128 = exactly 2 per lane)
    const int2 lab = ((const int2*)(labels + b * L_DIM))[l];
    const int c0 = lab.x, c1 = lab.y;
    int cB;  // blank idx in a VGPR (keep init load on vmem path, not SMEM)
    asm("v_mov_b32 %0, 255" : "=v"(cB));

    const int labprev = __shfl_up(c1, 1, 64);
    const double k1 = (l == 0 || labprev == c0) ? 0.0 : 1.0;  // skip into 4l+1
    const double k3 = (c1 == c0) ? 0.0 : 1.0;                 // skip into 4l+3

    // t = 0 init: alpha0[0] = p'(0,blank), alpha0[1] = p'(0,label0)
    double a0 = (double)(Yb[cB] + EPSF);
    double r1 = (l == 0) ? (double)(Yb[c0] + EPSF) : 0.0;
    double r2 = 0.0, r3 = 0.0, r4 = 0.0;
    int e2acc = 0;

    // ---- pipeline state ----
    float4 rbuf[DG];               // row g lives in rbuf[g & 7] until ds_write
    float fr0[4], fr1[4], frB[4];  // scalar ring: row r in slot r & 3

    // prologue: rbuf <- rows 4..11 (what steady iters t<=0 would have loaded)
#pragma unroll
    for (int g = DL + 1; g <= DL + DG; ++g)
        rbuf[g & 7] = ((const float4*)(Yb + (size_t)g * C_DIM))[l];
    // LDS <- rows 1..3 (slots 1..3 of the 4-ring)
#pragma unroll
    for (int w = 1; w <= DL; ++w) {
        float4 v = ((const float4*)(Yb + (size_t)w * C_DIM))[l];
        ((float4*)(smem + (w & 3) * C_DIM))[l] = v;
    }
    // scalar ring <- rows 1..2 (same-wave LDS ops are in-order: no barrier)
#pragma unroll
    for (int r = 1; r <= DS; ++r) {
        const float* row = smem + (r & 3) * C_DIM;
        fr0[r & 3] = row[c0]; fr1[r & 3] = row[c1]; frB[r & 3] = row[255];
    }

    // main loop: 63 chunks of 16 cover t = 1..1008 (tb = 1 mod 16 -> all
    // ring indices are compile-time constants after unrolling)
    for (int tb = 1; tb <= 993; tb += 16) {
#pragma unroll
        for (int d = 0; d < 16; ++d) {
            const int t = tb + d;
            // 1) ds_read scalars for row t+DS into ring slot (t+DS)&3
            {
                const float* row = smem + ((t + DS) & 3) * C_DIM;
                fr0[(t + DS) & 3] = row[c0];
                fr1[(t + DS) & 3] = row[c1];
                frB[(t + DS) & 3] = row[255];
            }
            // 2) ds_write row t+DL from rbuf, then 3) reload that rbuf slot
            {
                const int rs = (t + DL) & 7;       // rbuf slot
                const int ls = (t + DL) & 3;       // LDS slot
                ((float4*)(smem + ls * C_DIM))[l] = rbuf[rs];
                int g = t + DL + DG; g = g > T_DIM - 1 ? T_DIM - 1 : g;
                rbuf[rs] = ((const float4*)(Yb + (size_t)g * C_DIM))[l];
            }
            // 4) compute step t from ring slot t&3
            ctc_step((double)(fr0[t & 3] + EPSF), (double)(fr1[t & 3] + EPSF),
                     (double)(frB[t & 3] + EPSF), k1, k3, a0, r1, r2, r3, r4);
        }
        // rescale by exact power of two (exponent = int max of f64 hi words)
        int h = __double2hiint(r1);
        int t_;
        t_ = __double2hiint(r2); h = h > t_ ? h : t_;
        t_ = __double2hiint(r3); h = h > t_ ? h : t_;
        t_ = __double2hiint(r4); h = h > t_ ? h : t_;
        t_ = __double2hiint(a0); h = h > t_ ? h : t_;
        int H = wave_imax_all(h);
        int k = (H >> 20) - 1023;
        double s = __hiloint2double((1023 - k) << 20, 0);  // exact 2^-k
        r1 *= s; r2 *= s; r3 *= s; r4 *= s; a0 *= s;
        e2acc += k;
    }

    // tail: t = 1009..1023 — identical body (clamped rbuf reload keeps rows
    // 1020..1022 flowing; t>=1012 dup-loads row 1023, consumed never)
#pragma unroll
    for (int t = 1009; t <= 1023; ++t) {
        {
            const float* row = smem + ((t + DS) & 3) * C_DIM;
            fr0[(t + DS) & 3] = row[c0];
            fr1[(t + DS) & 3] = row[c1];
            frB[(t + DS) & 3] = row[255];
        }
        {
            const int rs = (t + DL) & 7;
            const int ls = (t + DL) & 3;
            ((float4*)(smem + ls * C_DIM))[l] = rbuf[rs];
            int g = t + DL + DG; g = g > T_DIM - 1 ? T_DIM - 1 : g;
            rbuf[rs] = ((const float4*)(Yb + (size_t)g * C_DIM))[l];
        }
        ctc_step((double)(fr0[t & 3] + EPSF), (double)(fr1[t & 3] + EPSF),
                 (double)(frB[t & 3] + EPSF), k1, k3, a0, r1, r2, r3, r4);
    }

    // loss = -( ln(A[255]+A[256]) + ln2 * e2acc ); states 255,256 = lane63 r3,r4
    if (l == 63) {
        double sum = r3 + r4;
        int hi = __double2hiint(sum), lo = __double2loint(sum);
        int e = (hi >> 20) - 1023;
        double mant = __hiloint2double((hi & 0x000FFFFF) | (1023 << 20), lo);
        double lg2 = (double)__log2f((float)mant) + (double)(e + e2acc);
        out[b] = (float)(-LN2D * lg2);
    }
}

extern "C" void kernel_launch(void* const* d_in, const int* in_sizes, int n_in,
                              void* d_out, int out_size, void* d_ws, size_t ws_size,
                              hipStream_t stream) {
    const int* y_true = (const int*)d_in[0];     // [256,128] int32
    const float* y_pred = (const float*)d_in[1]; // [256,1024,256] fp32
    float* out = (float*)d_out;                  // [256,1] fp32
    ctc_fwd<<<256 / WPB, WPB * 64, 0, stream>>>(y_true, y_pred, out);
}

// Round 6
// 367.972 us; speedup vs baseline: 1.9304x; 1.9304x over previous
//
#include <hip/hip_runtime.h>

// CTC forward loss, linear-space (scaled) forward algorithm, fp64 alpha.
// B=256, T=1024, C=256 (blank=255), L=128, S=2L+1=257.
// One 64-lane wave per batch element, 256 blocks x 64 threads (1 wave/CU).
// Lane l holds states 4l+1..4l+4 (fp64) + replicated state 0; neighbors via
// DPP WAVE_SHR1. No barriers (single wave per block).
//
// Round-4/5 post-mortem: every per-step round-robin pipeline ran at
// tau ~= one memory round-trip per step (600-1088 cy) -- the loop-carried
// load registers serialize. Under TLP the same step cost only ~137 cy,
// proving compute is cheap once latency is hidden. With only B=256 waves,
// TLP can't be increased (1 wave/CU is mandatory for full-machine use), so
// this round hides latency with the m97 staging shape instead:
//   per 16-step chunk: issue 16 async global_load_lds row-DMAs (next
//   chunk, no dest VGPRs), compute 14 steps from current LDS buffer
//   (~1800 cy > HBM latency), ONE s_waitcnt vmcnt(0) (free by then), then
//   2 boundary steps reading the next buffer. One vmem wait per 16 steps.

#define T_DIM 1024
#define C_DIM 256
#define L_DIM 128
#define EPSF  1e-7f
#define LN2D  0.69314718055994530942

typedef const __attribute__((address_space(1))) void* as1_cvp;
typedef __attribute__((address_space(3))) void* as3_vp;

// async DMA one 1 KB row (64 lanes x 16 B) global -> LDS; counts on vmcnt.
// ldsrow must be wave-uniform; HW writes lane i at ldsrow + 16*i.
__device__ __forceinline__ void gload_lds_row(const float* grow, int lane,
                                              float* ldsrow) {
    __builtin_amdgcn_global_load_lds((as1_cvp)(grow + 4 * lane),
                                     (as3_vp)ldsrow, 16, 0, 0);
}

// shuffle-up-by-1 across the 64-lane wave (both halves); lane 0 gets `old`.
__device__ __forceinline__ double dpp_shr1_f64(double old, double v) {
    int rlo = __builtin_amdgcn_update_dpp(__double2loint(old), __double2loint(v),
                                          0x138 /*WAVE_SHR1*/, 0xF, 0xF, false);
    int rhi = __builtin_amdgcn_update_dpp(__double2hiint(old), __double2hiint(v),
                                          0x138 /*WAVE_SHR1*/, 0xF, 0xF, false);
    return __hiloint2double(rhi, rlo);
}

// wave-wide int max (inputs >= 0), result broadcast via readlane(63).
__device__ __forceinline__ int wave_imax_all(int v) {
#define STAGE(CTRL) { int t_ = __builtin_amdgcn_update_dpp(v, v, CTRL, 0xF, 0xF, false); \
                      v = v > t_ ? v : t_; }
    STAGE(0x111)  // row_shr:1
    STAGE(0x112)  // row_shr:2
    STAGE(0x114)  // row_shr:4
    STAGE(0x118)  // row_shr:8
    STAGE(0x142)  // row_bcast:15
    STAGE(0x143)  // row_bcast:31
#undef STAGE
    return __builtin_amdgcn_readlane(v, 63);
}

__device__ __forceinline__ void ctc_step(double p0, double p1, double pB,
                                         double k1, double k3, double& a0,
                                         double& r1, double& r2, double& r3, double& r4) {
    // neighbors from previous lane: A[4l] = prev.r4, A[4l-1] = prev.r3
    double sA4 = dpp_shr1_f64(a0,  r4);   // lane0 <- state 0 (a0)
    double sA3 = dpp_shr1_f64(0.0, r3);   // lane0 <- 0 (state -1)
    double n1 = p0 * fma(k1, sA3, r1 + sA4);  // odd state 4l+1 (label 2l)
    double n2 = pB * (r2 + r1);               // blank state 4l+2
    double n3 = p1 * fma(k3, r1, r3 + r2);    // odd state 4l+3 (label 2l+1)
    double n4 = pB * (r4 + r3);               // blank state 4l+4
    a0 *= pB;                                 // state 0: blank self-loop only
    r1 = n1; r2 = n2; r3 = n3; r4 = n4;
}

#define DS_READ_ROW(rowptr) do {                                   \
        fr0[(t + 2) & 3] = (rowptr)[c0];                           \
        fr1[(t + 2) & 3] = (rowptr)[c1];                           \
        frB[(t + 2) & 3] = (rowptr)[255];                          \
    } while (0)

#define DO_STEP()                                                             \
    ctc_step((double)(fr0[t & 3] + EPSF), (double)(fr1[t & 3] + EPSF),        \
             (double)(frB[t & 3] + EPSF), k1, k3, a0, r1, r2, r3, r4)

__global__ __launch_bounds__(64, 1)
void ctc_fwd(const int* __restrict__ labels, const float* __restrict__ ypred,
             float* __restrict__ out) {
    const int b = blockIdx.x;
    const int l = threadIdx.x;  // lane 0..63
    const float* Yb = ypred + (size_t)b * (T_DIM * C_DIM);

    // two 16-row buffers; row r (r>=1) -> chunk c=(r-1)>>4, slot (r-1)&15,
    // buffer c&1. 32 KB total.
    __shared__ float smem[2 * 16 * C_DIM];

    // labels 2l, 2l+1 (L=128 = exactly 2 per lane)
    const int2 lab = ((const int2*)(labels + b * L_DIM))[l];
    const int c0 = lab.x, c1 = lab.y;
    int cB;  // blank idx in a VGPR (keep init load on vmem path, not SMEM)
    asm("v_mov_b32 %0, 255" : "=v"(cB));

    const int labprev = __shfl_up(c1, 1, 64);
    const double k1 = (l == 0 || labprev == c0) ? 0.0 : 1.0;  // skip into 4l+1
    const double k3 = (c1 == c0) ? 0.0 : 1.0;                 // skip into 4l+3

    // t = 0 init: alpha0[0] = p'(0,blank), alpha0[1] = p'(0,label0)
    double a0 = (double)(Yb[cB] + EPSF);
    double r1 = (l == 0) ? (double)(Yb[c0] + EPSF) : 0.0;
    double r2 = 0.0, r3 = 0.0, r4 = 0.0;
    int e2acc = 0;

    float fr0[4], fr1[4], frB[4];  // scalar ring: row r in slot r & 3

    // prologue: stage chunk 0 (rows 1..16) into buf0; drain; seed fr rows 1,2
#pragma unroll
    for (int j = 0; j < 16; ++j)
        gload_lds_row(Yb + (size_t)(1 + j) * C_DIM, l, smem + j * C_DIM);
    asm volatile("s_waitcnt vmcnt(0)" ::: "memory");
#pragma unroll
    for (int r = 1; r <= 2; ++r) {
        const float* row = smem + (r - 1) * C_DIM;
        fr0[r & 3] = row[c0]; fr1[r & 3] = row[c1]; frB[r & 3] = row[255];
    }

    // main loop: chunks k=0..62, compute t = 1+16k .. 16+16k (1..1008)
    for (int k = 0; k < 63; ++k) {
        // 1) issue async staging of chunk k+1 (rows 17+16k..32+16k, clamped)
        {
            const int g0 = 17 + 16 * k;
            float* dst = smem + ((k + 1) & 1) * (16 * C_DIM);
#pragma unroll
            for (int j = 0; j < 16; ++j) {
                int g = g0 + j; g = g > T_DIM - 1 ? T_DIM - 1 : g;
                gload_lds_row(Yb + (size_t)g * C_DIM, l, dst + j * C_DIM);
            }
        }
        const int tb = 1 + 16 * k;
        const float* bufk = smem + (k & 1) * (16 * C_DIM);
        const float* bufn = smem + ((k + 1) & 1) * (16 * C_DIM);
        // 2) 14 steps reading ahead (row t+2) from the CURRENT buffer;
        //    slot of row t+2 = (t+1)&15 = (2+d)&15 -> compile-time const
#pragma unroll
        for (int d = 0; d < 14; ++d) {
            const int t = tb + d;
            const float* row = bufk + ((2 + d) & 15) * C_DIM;
            DS_READ_ROW(row);
            DO_STEP();
        }
        // 3) one drain for chunk k+1 (issued ~14 steps = ~1800 cy ago: free)
        asm volatile("s_waitcnt vmcnt(0)" ::: "memory");
        // 4) boundary steps whose read-ahead rows live in the NEXT buffer
#pragma unroll
        for (int d = 14; d < 16; ++d) {
            const int t = tb + d;
            const float* row = bufn + ((2 + d) & 15) * C_DIM;  // slots 0,1
            DS_READ_ROW(row);
            DO_STEP();
        }
        // 5) rescale by exact power of two (exponent = max of f64 hi words)
        int h = __double2hiint(r1);
        int t_;
        t_ = __double2hiint(r2); h = h > t_ ? h : t_;
        t_ = __double2hiint(r3); h = h > t_ ? h : t_;
        t_ = __double2hiint(r4); h = h > t_ ? h : t_;
        t_ = __double2hiint(a0); h = h > t_ ? h : t_;
        int H = wave_imax_all(h);
        int kk = (H >> 20) - 1023;
        double s = __hiloint2double((1023 - kk) << 20, 0);  // exact 2^-kk
        r1 *= s; r2 *= s; r3 *= s; r4 *= s; a0 *= s;
        e2acc += kk;
    }

    // tail: t = 1009..1023 from chunk 63 (buf 1, staged during k=62).
    // read-ahead rows clamp to 1023; the over-read slots are never consumed.
    {
        const float* buft = smem + (63 & 1) * (16 * C_DIM);
#pragma unroll
        for (int t = 1009; t <= 1023; ++t) {
            int rr = t + 2; rr = rr > T_DIM - 1 ? T_DIM - 1 : rr;
            const float* row = buft + ((rr - 1) & 15) * C_DIM;
            DS_READ_ROW(row);
            DO_STEP();
        }
    }

    // loss = -( ln(A[255]+A[256]) + ln2 * e2acc ); states 255,256 = lane63 r3,r4
    if (l == 63) {
        double sum = r3 + r4;
        int hi = __double2hiint(sum), lo = __double2loint(sum);
        int e = (hi >> 20) - 1023;
        double mant = __hiloint2double((hi & 0x000FFFFF) | (1023 << 20), lo);
        double lg2 = (double)__log2f((float)mant) + (double)(e + e2acc);
        out[b] = (float)(-LN2D * lg2);
    }
}

extern "C" void kernel_launch(void* const* d_in, const int* in_sizes, int n_in,
                              void* d_out, int out_size, void* d_ws, size_t ws_size,
                              hipStream_t stream) {
    const int* y_true = (const int*)d_in[0];     // [256,128] int32
    const float* y_pred = (const float*)d_in[1]; // [256,1024,256] fp32
    float* out = (float*)d_out;                  // [256,1] fp32
    ctc_fwd<<<256, 64, 0, stream>>>(y_true, y_pred, out);
}